// Round 2
// baseline (453.080 us; speedup 1.0000x reference)
//
#include <hip/hip_runtime.h>

#define NCLS 21
#define HW   (512 * 512)            // pixels per plane (2^18)
#define NB   16                     // batch
#define NPIX (NB * HW)              // 4,194,304 pixels
#define PXT  8                      // pixels per thread
#define NTH  (NPIX / PXT)           // 524,288 threads
#define BLK  256
#define GRID (NTH / BLK)            // 2048 blocks, exact

typedef float v4f __attribute__((ext_vector_type(4)));
typedef int   v4i __attribute__((ext_vector_type(4)));

__device__ __forceinline__ v4f ntload(const float* p) {
    // pred is read-once (352 MB > 256 MB L3): bypass cache retention.
    return __builtin_nontemporal_load((const v4f*)p);
}

// cnt layout: [0..20] inter, [21..41] cp, [42..62] cg, [63] block ticket.
__global__ void __launch_bounds__(BLK) iou_kernel(
    const float* __restrict__ pred, const int* __restrict__ gt,
    unsigned int* __restrict__ cnt, float* __restrict__ out) {

    __shared__ unsigned int h[3 * NCLS];
    __shared__ unsigned int ticket;
    for (int i = threadIdx.x; i < 3 * NCLS; i += BLK) h[i] = 0u;
    __syncthreads();

    const int v  = blockIdx.x * BLK + threadIdx.x;    // 0..NTH-1
    const int p0 = v << 3;                            // first of 8 pixels
    const int b  = p0 >> 18;                          // p0 / HW
    const int hw = p0 & (HW - 1);                     // p0 % HW (multiple of 8)
    const float* base = pred + (size_t)b * (NCLS * HW) + hw;

    v4f m0 = ntload(base);
    v4f m1 = ntload(base + 4);
    int i0 = 0, i1 = 0, i2 = 0, i3 = 0, i4 = 0, i5 = 0, i6 = 0, i7 = 0;
#pragma unroll
    for (int c = 1; c < NCLS; ++c) {
        const float* pc = base + (size_t)c * HW;
        v4f x0 = ntload(pc);
        v4f x1 = ntload(pc + 4);
        if (x0.x > m0.x) { m0.x = x0.x; i0 = c; }   // strict > keeps first max (jnp tie-break)
        if (x0.y > m0.y) { m0.y = x0.y; i1 = c; }
        if (x0.z > m0.z) { m0.z = x0.z; i2 = c; }
        if (x0.w > m0.w) { m0.w = x0.w; i3 = c; }
        if (x1.x > m1.x) { m1.x = x1.x; i4 = c; }
        if (x1.y > m1.y) { m1.y = x1.y; i5 = c; }
        if (x1.z > m1.z) { m1.z = x1.z; i6 = c; }
        if (x1.w > m1.w) { m1.w = x1.w; i7 = c; }
    }

    const v4i g0 = *(const v4i*)(gt + p0);
    const v4i g1 = *(const v4i*)(gt + p0 + 4);

    atomicAdd(&h[NCLS + i0], 1u);
    atomicAdd(&h[NCLS + i1], 1u);
    atomicAdd(&h[NCLS + i2], 1u);
    atomicAdd(&h[NCLS + i3], 1u);
    atomicAdd(&h[NCLS + i4], 1u);
    atomicAdd(&h[NCLS + i5], 1u);
    atomicAdd(&h[NCLS + i6], 1u);
    atomicAdd(&h[NCLS + i7], 1u);
    atomicAdd(&h[2 * NCLS + g0.x], 1u);
    atomicAdd(&h[2 * NCLS + g0.y], 1u);
    atomicAdd(&h[2 * NCLS + g0.z], 1u);
    atomicAdd(&h[2 * NCLS + g0.w], 1u);
    atomicAdd(&h[2 * NCLS + g1.x], 1u);
    atomicAdd(&h[2 * NCLS + g1.y], 1u);
    atomicAdd(&h[2 * NCLS + g1.z], 1u);
    atomicAdd(&h[2 * NCLS + g1.w], 1u);
    if (i0 == g0.x) atomicAdd(&h[i0], 1u);
    if (i1 == g0.y) atomicAdd(&h[i1], 1u);
    if (i2 == g0.z) atomicAdd(&h[i2], 1u);
    if (i3 == g0.w) atomicAdd(&h[i3], 1u);
    if (i4 == g1.x) atomicAdd(&h[i4], 1u);
    if (i5 == g1.y) atomicAdd(&h[i5], 1u);
    if (i6 == g1.z) atomicAdd(&h[i6], 1u);
    if (i7 == g1.w) atomicAdd(&h[i7], 1u);

    __syncthreads();
    for (int i = threadIdx.x; i < 3 * NCLS; i += BLK) {
        unsigned int val = h[i];
        if (val) atomicAdd(&cnt[i], val);           // device-scope (G12)
    }
    __threadfence();        // order our cnt RMWs before the ticket RMW
    __syncthreads();        // drains vmcnt: all this block's atomics complete

    if (threadIdx.x == 0) ticket = atomicAdd(&cnt[63], 1u);
    __syncthreads();

    if (ticket == GRID - 1) {                       // last block finalizes
        __shared__ float sIou[NCLS];
        if (threadIdx.x < NCLS) {
            // atomic RMW reads guarantee coherent view across XCDs (G16)
            const float inter = (float)atomicOr(&cnt[threadIdx.x], 0u);
            const float cp    = (float)atomicOr(&cnt[NCLS + threadIdx.x], 0u);
            const float cg    = (float)atomicOr(&cnt[2 * NCLS + threadIdx.x], 0u);
            const float uni   = cp + cg - inter;
            sIou[threadIdx.x] =
                (inter > 0.0f) ? inter / (uni > 0.0f ? uni : 1.0f) : 0.0f;
        }
        __syncthreads();
        if (threadIdx.x == 0) {
            float s = 0.0f;
#pragma unroll
            for (int c = 0; c < NCLS; ++c) s += sIou[c];
            out[0] = s / (float)NCLS;
        }
    }
}

extern "C" void kernel_launch(void* const* d_in, const int* in_sizes, int n_in,
                              void* d_out, int out_size, void* d_ws, size_t ws_size,
                              hipStream_t stream) {
    const float*  pred = (const float*)d_in[0];
    const int*    gt   = (const int*)d_in[1];
    float*        out  = (float*)d_out;
    unsigned int* cnt  = (unsigned int*)d_ws;

    // d_ws is poisoned (0xAA) once and never re-poisoned: zero counters +
    // ticket every call (64 uints).
    hipMemsetAsync(cnt, 0, 64 * sizeof(unsigned int), stream);

    iou_kernel<<<GRID, BLK, 0, stream>>>(pred, gt, cnt, out);
}

// Round 3
// 82.558 us; speedup vs baseline: 5.4880x; 5.4880x over previous
//
#include <hip/hip_runtime.h>

#define NCLS 21
#define HW   (512 * 512)            // pixels per plane (2^18)
#define NB   16                     // batch
#define NPIX (NB * HW)              // 4,194,304 pixels
#define NVEC (NPIX / 4)             // 1,048,576 float4 groups
#define BLK  256
#define GRID 2048
#define NTHREADS (GRID * BLK)       // 524,288 -> 2 grid-stride iterations

typedef float v4f __attribute__((ext_vector_type(4)));
typedef int   v4i __attribute__((ext_vector_type(4)));

// Phase 1: per-pixel argmax over 21 classes + LDS histograms -> global counters.
// cnt layout: [0..20] inter, [21..41] cp (pred counts), [42..62] cg (gt counts)
__global__ void __launch_bounds__(BLK) iou_hist_kernel(
    const float* __restrict__ pred, const int* __restrict__ gt,
    unsigned int* __restrict__ cnt) {
    __shared__ unsigned int h[3 * NCLS];
    for (int i = threadIdx.x; i < 3 * NCLS; i += BLK) h[i] = 0u;
    __syncthreads();

    for (int v = blockIdx.x * BLK + threadIdx.x; v < NVEC; v += NTHREADS) {
        const int p0 = v << 2;            // first pixel of this 4-group
        const int b  = p0 >> 18;          // p0 / HW
        const int hw = p0 & (HW - 1);     // p0 % HW (multiple of 4)
        const float* base = pred + (size_t)b * (NCLS * HW) + hw;

        // Prefetch ALL class vectors first: 21 independent 16B loads in
        // flight per wave (statically indexed -> registers, rule #20).
        v4f x[NCLS];
#pragma unroll
        for (int c = 0; c < NCLS; ++c)
            x[c] = *(const v4f*)(base + (size_t)c * HW);
        const v4i g = *(const v4i*)(gt + p0);

        v4f m = x[0];
        int ix = 0, iy = 0, iz = 0, iw = 0;
#pragma unroll
        for (int c = 1; c < NCLS; ++c) {
            // strict > keeps first max (jnp argmax tie-break)
            if (x[c].x > m.x) { m.x = x[c].x; ix = c; }
            if (x[c].y > m.y) { m.y = x[c].y; iy = c; }
            if (x[c].z > m.z) { m.z = x[c].z; iz = c; }
            if (x[c].w > m.w) { m.w = x[c].w; iw = c; }
        }

        atomicAdd(&h[NCLS + ix], 1u);
        atomicAdd(&h[NCLS + iy], 1u);
        atomicAdd(&h[NCLS + iz], 1u);
        atomicAdd(&h[NCLS + iw], 1u);
        atomicAdd(&h[2 * NCLS + g.x], 1u);
        atomicAdd(&h[2 * NCLS + g.y], 1u);
        atomicAdd(&h[2 * NCLS + g.z], 1u);
        atomicAdd(&h[2 * NCLS + g.w], 1u);
        if (ix == g.x) atomicAdd(&h[ix], 1u);
        if (iy == g.y) atomicAdd(&h[iy], 1u);
        if (iz == g.z) atomicAdd(&h[iz], 1u);
        if (iw == g.w) atomicAdd(&h[iw], 1u);
    }

    __syncthreads();
    for (int i = threadIdx.x; i < 3 * NCLS; i += BLK) {
        unsigned int val = h[i];
        if (val) atomicAdd(&cnt[i], val);   // device-scope by default (G12)
    }
}

// Phase 2: one wave computes per-class IoU and the mean.
__global__ void iou_final_kernel(const unsigned int* __restrict__ cnt,
                                 float* __restrict__ out) {
    const int lane = threadIdx.x;
    float iou = 0.0f;
    if (lane < NCLS) {
        const float inter = (float)cnt[lane];
        const float cp    = (float)cnt[NCLS + lane];
        const float cg    = (float)cnt[2 * NCLS + lane];
        const float uni   = cp + cg - inter;
        iou = (inter > 0.0f) ? inter / (uni > 0.0f ? uni : 1.0f) : 0.0f;
    }
#pragma unroll
    for (int off = 32; off >= 1; off >>= 1)
        iou += __shfl_down(iou, off, 64);
    if (lane == 0) out[0] = iou / (float)NCLS;
}

extern "C" void kernel_launch(void* const* d_in, const int* in_sizes, int n_in,
                              void* d_out, int out_size, void* d_ws, size_t ws_size,
                              hipStream_t stream) {
    const float*  pred = (const float*)d_in[0];
    const int*    gt   = (const int*)d_in[1];
    float*        out  = (float*)d_out;
    unsigned int* cnt  = (unsigned int*)d_ws;

    // d_ws is poisoned once (0xAA) and never re-poisoned: zero it every call.
    hipMemsetAsync(cnt, 0, 3 * NCLS * sizeof(unsigned int), stream);

    iou_hist_kernel<<<GRID, BLK, 0, stream>>>(pred, gt, cnt);
    iou_final_kernel<<<1, 64, 0, stream>>>(cnt, out);
}

// Round 4
// 75.804 us; speedup vs baseline: 5.9770x; 1.0891x over previous
//
#include <hip/hip_runtime.h>

#define NCLS 21
#define HW   (512 * 512)            // pixels per plane (2^18)
#define NB   16                     // batch
#define NPIX (NB * HW)              // 4,194,304 pixels
#define NVEC (NPIX / 4)             // 1,048,576 float4 groups
#define BLK  1024                   // 16 waves -> 16KB contiguous per class-stream
#define GRID 512                    // 2 blocks/CU resident (VGPR<=64) -> all resident
#define NTHREADS (GRID * BLK)       // 524,288 -> 2 grid-stride iterations

typedef float v4f __attribute__((ext_vector_type(4)));
typedef int   v4i __attribute__((ext_vector_type(4)));

// Phase 1: per-pixel argmax over 21 classes + LDS histograms -> global counters.
// cnt layout: [0..20] inter, [21..41] cp (pred counts), [42..62] cg (gt counts)
__global__ void __launch_bounds__(BLK) iou_hist_kernel(
    const float* __restrict__ pred, const int* __restrict__ gt,
    unsigned int* __restrict__ cnt) {
    __shared__ unsigned int h[3 * NCLS];
    for (int i = threadIdx.x; i < 3 * NCLS; i += BLK) h[i] = 0u;
    __syncthreads();

    for (int v = blockIdx.x * BLK + threadIdx.x; v < NVEC; v += NTHREADS) {
        const int p0 = v << 2;            // first pixel of this 4-group
        const int b  = p0 >> 18;          // p0 / HW
        const int hw = p0 & (HW - 1);     // p0 % HW (multiple of 4)
        const float* base = pred + (size_t)b * (NCLS * HW) + hw;

        v4f m = *(const v4f*)base;
        int ix = 0, iy = 0, iz = 0, iw = 0;
#pragma unroll
        for (int c = 1; c < NCLS; ++c) {
            const v4f x = *(const v4f*)(base + (size_t)c * HW);
            // strict > keeps first max (jnp argmax tie-break)
            if (x.x > m.x) { m.x = x.x; ix = c; }
            if (x.y > m.y) { m.y = x.y; iy = c; }
            if (x.z > m.z) { m.z = x.z; iz = c; }
            if (x.w > m.w) { m.w = x.w; iw = c; }
        }
        const v4i g = *(const v4i*)(gt + p0);

        atomicAdd(&h[NCLS + ix], 1u);
        atomicAdd(&h[NCLS + iy], 1u);
        atomicAdd(&h[NCLS + iz], 1u);
        atomicAdd(&h[NCLS + iw], 1u);
        atomicAdd(&h[2 * NCLS + g.x], 1u);
        atomicAdd(&h[2 * NCLS + g.y], 1u);
        atomicAdd(&h[2 * NCLS + g.z], 1u);
        atomicAdd(&h[2 * NCLS + g.w], 1u);
        if (ix == g.x) atomicAdd(&h[ix], 1u);
        if (iy == g.y) atomicAdd(&h[iy], 1u);
        if (iz == g.z) atomicAdd(&h[iz], 1u);
        if (iw == g.w) atomicAdd(&h[iw], 1u);
    }

    __syncthreads();
    for (int i = threadIdx.x; i < 3 * NCLS; i += BLK) {
        unsigned int val = h[i];
        if (val) atomicAdd(&cnt[i], val);   // device-scope by default (G12)
    }
}

// Phase 2: one wave computes per-class IoU and the mean.
__global__ void iou_final_kernel(const unsigned int* __restrict__ cnt,
                                 float* __restrict__ out) {
    const int lane = threadIdx.x;
    float iou = 0.0f;
    if (lane < NCLS) {
        const float inter = (float)cnt[lane];
        const float cp    = (float)cnt[NCLS + lane];
        const float cg    = (float)cnt[2 * NCLS + lane];
        const float uni   = cp + cg - inter;
        iou = (inter > 0.0f) ? inter / (uni > 0.0f ? uni : 1.0f) : 0.0f;
    }
#pragma unroll
    for (int off = 32; off >= 1; off >>= 1)
        iou += __shfl_down(iou, off, 64);
    if (lane == 0) out[0] = iou / (float)NCLS;
}

extern "C" void kernel_launch(void* const* d_in, const int* in_sizes, int n_in,
                              void* d_out, int out_size, void* d_ws, size_t ws_size,
                              hipStream_t stream) {
    const float*  pred = (const float*)d_in[0];
    const int*    gt   = (const int*)d_in[1];
    float*        out  = (float*)d_out;
    unsigned int* cnt  = (unsigned int*)d_ws;

    // d_ws is poisoned once (0xAA) and never re-poisoned: zero it every call.
    hipMemsetAsync(cnt, 0, 3 * NCLS * sizeof(unsigned int), stream);

    iou_hist_kernel<<<GRID, BLK, 0, stream>>>(pred, gt, cnt);
    iou_final_kernel<<<1, 64, 0, stream>>>(cnt, out);
}

// Round 5
// 75.125 us; speedup vs baseline: 6.0310x; 1.0090x over previous
//
#include <hip/hip_runtime.h>

#define NCLS 21
#define HW   (512 * 512)            // pixels per plane (2^18)
#define NB   16                     // batch
#define NPIX (NB * HW)              // 4,194,304 pixels
#define BLK  1024
#define SEG  8192                   // pixels per block: 2 chunks x 4096
#define CHUNK 4096                  // pixels per chunk (BLK * 4)
#define GRID (NPIX / SEG)           // 512 blocks, exact

typedef float v4f __attribute__((ext_vector_type(4)));
typedef int   v4i __attribute__((ext_vector_type(4)));

// Phase 1: per-pixel argmax over 21 classes + LDS histograms -> global counters.
// cnt layout: [0..20] inter, [21..41] cp (pred counts), [42..62] cg (gt counts)
// Each block owns a 32KB (8192-pixel) contiguous segment per class; per class
// it issues two back-to-back fully-coalesced 16KB dwordx4 loads (chunk A/B),
// so each class-stream is a 32KB contiguous burst per block.
__global__ void __launch_bounds__(BLK) iou_hist_kernel(
    const float* __restrict__ pred, const int* __restrict__ gt,
    unsigned int* __restrict__ cnt) {
    __shared__ unsigned int h[3 * NCLS];
    for (int i = threadIdx.x; i < 3 * NCLS; i += BLK) h[i] = 0u;
    __syncthreads();

    const int p0 = blockIdx.x * SEG + threadIdx.x * 4;  // chunk A first pixel
    // SEG (8192) divides HW (2^18), so chunks A and B sit in the same image.
    const int b  = p0 >> 18;                            // p0 / HW
    const int hw = p0 & (HW - 1);                       // p0 % HW
    const float* base = pred + (size_t)b * (NCLS * HW) + hw;

    v4f mA = *(const v4f*)base;
    v4f mB = *(const v4f*)(base + CHUNK);
    int a0 = 0, a1 = 0, a2 = 0, a3 = 0;
    int b0 = 0, b1 = 0, b2 = 0, b3 = 0;
#pragma unroll
    for (int c = 1; c < NCLS; ++c) {
        const float* pc = base + (size_t)c * HW;
        const v4f xA = *(const v4f*)pc;
        const v4f xB = *(const v4f*)(pc + CHUNK);
        // strict > keeps first max (jnp argmax tie-break)
        if (xA.x > mA.x) { mA.x = xA.x; a0 = c; }
        if (xA.y > mA.y) { mA.y = xA.y; a1 = c; }
        if (xA.z > mA.z) { mA.z = xA.z; a2 = c; }
        if (xA.w > mA.w) { mA.w = xA.w; a3 = c; }
        if (xB.x > mB.x) { mB.x = xB.x; b0 = c; }
        if (xB.y > mB.y) { mB.y = xB.y; b1 = c; }
        if (xB.z > mB.z) { mB.z = xB.z; b2 = c; }
        if (xB.w > mB.w) { mB.w = xB.w; b3 = c; }
    }
    const v4i gA = *(const v4i*)(gt + p0);
    const v4i gB = *(const v4i*)(gt + p0 + CHUNK);

    atomicAdd(&h[NCLS + a0], 1u);
    atomicAdd(&h[NCLS + a1], 1u);
    atomicAdd(&h[NCLS + a2], 1u);
    atomicAdd(&h[NCLS + a3], 1u);
    atomicAdd(&h[NCLS + b0], 1u);
    atomicAdd(&h[NCLS + b1], 1u);
    atomicAdd(&h[NCLS + b2], 1u);
    atomicAdd(&h[NCLS + b3], 1u);
    atomicAdd(&h[2 * NCLS + gA.x], 1u);
    atomicAdd(&h[2 * NCLS + gA.y], 1u);
    atomicAdd(&h[2 * NCLS + gA.z], 1u);
    atomicAdd(&h[2 * NCLS + gA.w], 1u);
    atomicAdd(&h[2 * NCLS + gB.x], 1u);
    atomicAdd(&h[2 * NCLS + gB.y], 1u);
    atomicAdd(&h[2 * NCLS + gB.z], 1u);
    atomicAdd(&h[2 * NCLS + gB.w], 1u);
    if (a0 == gA.x) atomicAdd(&h[a0], 1u);
    if (a1 == gA.y) atomicAdd(&h[a1], 1u);
    if (a2 == gA.z) atomicAdd(&h[a2], 1u);
    if (a3 == gA.w) atomicAdd(&h[a3], 1u);
    if (b0 == gB.x) atomicAdd(&h[b0], 1u);
    if (b1 == gB.y) atomicAdd(&h[b1], 1u);
    if (b2 == gB.z) atomicAdd(&h[b2], 1u);
    if (b3 == gB.w) atomicAdd(&h[b3], 1u);

    __syncthreads();
    for (int i = threadIdx.x; i < 3 * NCLS; i += BLK) {
        unsigned int val = h[i];
        if (val) atomicAdd(&cnt[i], val);   // device-scope by default (G12)
    }
}

// Phase 2: one wave computes per-class IoU and the mean.
__global__ void iou_final_kernel(const unsigned int* __restrict__ cnt,
                                 float* __restrict__ out) {
    const int lane = threadIdx.x;
    float iou = 0.0f;
    if (lane < NCLS) {
        const float inter = (float)cnt[lane];
        const float cp    = (float)cnt[NCLS + lane];
        const float cg    = (float)cnt[2 * NCLS + lane];
        const float uni   = cp + cg - inter;
        iou = (inter > 0.0f) ? inter / (uni > 0.0f ? uni : 1.0f) : 0.0f;
    }
#pragma unroll
    for (int off = 32; off >= 1; off >>= 1)
        iou += __shfl_down(iou, off, 64);
    if (lane == 0) out[0] = iou / (float)NCLS;
}

extern "C" void kernel_launch(void* const* d_in, const int* in_sizes, int n_in,
                              void* d_out, int out_size, void* d_ws, size_t ws_size,
                              hipStream_t stream) {
    const float*  pred = (const float*)d_in[0];
    const int*    gt   = (const int*)d_in[1];
    float*        out  = (float*)d_out;
    unsigned int* cnt  = (unsigned int*)d_ws;

    // d_ws is poisoned once (0xAA) and never re-poisoned: zero it every call.
    hipMemsetAsync(cnt, 0, 3 * NCLS * sizeof(unsigned int), stream);

    iou_hist_kernel<<<GRID, BLK, 0, stream>>>(pred, gt, cnt);
    iou_final_kernel<<<1, 64, 0, stream>>>(cnt, out);
}